// Round 1
// baseline (246.247 us; speedup 1.0000x reference)
//
#include <hip/hip_runtime.h>
#include <hip/hip_cooperative_groups.h>
#include <math.h>

namespace cg = cooperative_groups;

#define NGRID 128
#define NG2 (NGRID * NGRID)
#define NG3 (NGRID * NGRID * NGRID)
#define CH 32
#define RADC 4            // taps kept: K[5..8]/K[0] < 4e-6 — below fp32 noise vs 3e-2 threshold
#define YT 16             // y-tile height in fused conv phase (1024 tasks = 128 z * 8 tiles)
#define HALO RADC
#define ROWS (YT + 2 * HALO)           // 24
#define NTASK (NGRID * (NGRID / YT))   // 1024
#define CONV_LDS_BYTES (ROWS * NGRID * 4)   // 12 KB

constexpr float L_BOX = 10.0f;
constexpr float H = L_BOX / NGRID;   // 0.078125 — exact in fp32

struct Ktaps { float k[RADC + 1]; };

__device__ __forceinline__ float silu(float v) {
    return v / (1.0f + expf(-v));
}

// Per-lane window: lane handles tap (px,py,pz); returns weight and flat index.
__device__ __forceinline__ void lane_tap(const float* __restrict__ pos, int i, int lane,
                                         float& w, int& addr) {
    int px = lane & 3, py = (lane >> 2) & 3, pz = (lane >> 4) & 3;
    float pwx = fmodf(pos[i * 3 + 0], L_BOX);
    float pwy = fmodf(pos[i * 3 + 1], L_BOX);
    float pwz = fmodf(pos[i * 3 + 2], L_BOX);
    int bx = (int)floorf(pwx / H);
    int by = (int)floorf(pwy / H);
    int bz = (int)floorf(pwz / H);
    int cx = bx + px - 1, cy = by + py - 1, cz = bz + pz - 1;
    float dx = (pwx - (float)cx * H) / H;
    float dy = (pwy - (float)cy * H) / H;
    float dz = (pwz - (float)cz * H) / H;
    w = expf(-0.5f * dx * dx) * expf(-0.5f * dy * dy) * expf(-0.5f * dz * dz);
    int ix = (cx + NGRID) & (NGRID - 1);
    int iy = (cy + NGRID) & (NGRID - 1);
    int iz = (cz + NGRID) & (NGRID - 1);
    addr = iz * NG2 + iy * NGRID + ix;
}

// ---------------------------------------------------------------------------
// Fused persistent kernel: zero -> scatter(MLP) -> conv_xy -> gather_z with
// grid-wide syncs. All phases grid-strided so any co-resident grid size works.
// ---------------------------------------------------------------------------
__global__ void __launch_bounds__(256)
fused(const int* __restrict__ z, const float* __restrict__ pos,
      const float* __restrict__ emb,
      const float* __restrict__ W0, const float* __restrict__ b0,
      const float* __restrict__ W1, const float* __restrict__ b1,
      float* __restrict__ field1, float* __restrict__ field2,
      float* __restrict__ out, Ktaps K, int N) {
    cg::grid_group grid = cg::this_grid();
    __shared__ float sm[ROWS][NGRID];        // 12 KB
    const int tid  = threadIdx.x;
    const int wave = tid >> 6, lane = tid & 63;
    const int gsize = gridDim.x;

    // ---- phase 0: zero field1 (vectorized; replaces the rocclr fill node) ----
    {
        float4* f4 = (float4*)field1;
        const float4 zv = make_float4(0.f, 0.f, 0.f, 0.f);
        for (int idx = blockIdx.x * 256 + tid; idx < NG3 / 4; idx += gsize * 256)
            f4[idx] = zv;
    }
    grid.sync();

    // ---- phase 1: per-wave MLP + 64-tap atomic scatter ----
    for (int i = blockIdx.x * 4 + wave; i < N; i += gsize * 4) {
        int sub = lane & 31;                 // channel (both half-waves identical)
        int zi = z[i];
        float x = emb[zi * CH + sub];

        float acc = b0[sub];
#pragma unroll
        for (int k = 0; k < CH; ++k)
            acc = fmaf(__shfl(x, k, 32), W0[sub * CH + k], acc);
        float h1 = silu(acc);

        acc = b1[sub];
#pragma unroll
        for (int k = 0; k < CH; ++k)
            acc = fmaf(__shfl(h1, k, 32), W1[sub * CH + k], acc);
        float s = silu(acc);
#pragma unroll
        for (int m = 16; m >= 1; m >>= 1) s += __shfl_xor(s, m, 32);

        float w; int addr;
        lane_tap(pos, i, lane, w, addr);
        atomicAdd(&field1[addr], w * s);
    }
    grid.sync();

    // ---- phase 2: fused x+y circular conv, field1 -> field2 ----
    for (int task = blockIdx.x; task < NTASK; task += gsize) {
        int zpl = task >> 3;                 // z plane (8 y-tiles per plane)
        int y0  = (task & 7) * YT;
        __syncthreads();                     // guard sm reuse across task iterations

        const float4* plane4 = (const float4*)(field1 + zpl * NG2);
        for (int idx = tid; idx < ROWS * (NGRID / 4); idx += 256) {
            int row = idx >> 5, x4 = idx & 31;
            int gy = (y0 + row - HALO) & (NGRID - 1);
            ((float4*)sm[row])[x4] = plane4[gy * (NGRID / 4) + x4];
        }
        __syncthreads();

        // x-conv in place, wave-private rows (lockstep: reads issue before writes)
        for (int row = wave; row < ROWS; row += 4) {
            int t0 = lane, t1 = lane + 64;
            float a0 = K.k[0] * sm[row][t0];
            float a1 = K.k[0] * sm[row][t1];
#pragma unroll
            for (int r = 1; r <= RADC; ++r) {
                a0 += K.k[r] * (sm[row][(t0 + r) & 127] + sm[row][(t0 - r + 128) & 127]);
                a1 += K.k[r] * (sm[row][(t1 + r) & 127] + sm[row][(t1 - r + 128) & 127]);
            }
            sm[row][t0] = a0;
            sm[row][t1] = a1;
        }
        __syncthreads();

        // y-conv (halo covers +-RADC), coalesced write to field2
        int xl = tid & 127, yh = tid >> 7;
        float* oplane = field2 + zpl * NG2;
        for (int j = yh; j < YT; j += 2) {
            float acc = K.k[0] * sm[HALO + j][xl];
#pragma unroll
            for (int r = 1; r <= RADC; ++r)
                acc += K.k[r] * (sm[HALO + j + r][xl] + sm[HALO + j - r][xl]);
            oplane[(y0 + j) * NGRID + xl] = acc;
        }
    }
    grid.sync();

    // ---- phase 3: gather with z-conv folded into the particle z-window ----
    for (int i = blockIdx.x * 4 + wave; i < N; i += gsize * 4) {
        int px = lane & 3, py = (lane >> 2) & 3, zg = lane >> 4;   // zg = 0..3

        float pwx = fmodf(pos[i * 3 + 0], L_BOX);
        float pwy = fmodf(pos[i * 3 + 1], L_BOX);
        float pwz = fmodf(pos[i * 3 + 2], L_BOX);
        int bx = (int)floorf(pwx / H);
        int by = (int)floorf(pwy / H);
        int bz = (int)floorf(pwz / H);
        int cx = bx + px - 1, cy = by + py - 1;
        float dx = (pwx - (float)cx * H) / H;
        float dy = (pwy - (float)cy * H) / H;
        float wxy = expf(-0.5f * dx * dx) * expf(-0.5f * dy * dy);
        int ix = (cx + NGRID) & 127, iy = (cy + NGRID) & 127;

        float wz[4];
#pragma unroll
        for (int pz = 0; pz < 4; ++pz) {
            int cz = bz + pz - 1;
            float dz = (pwz - (float)cz * H) / H;
            wz[pz] = expf(-0.5f * dz * dz);
        }

        int xybase = iy * NGRID + ix;
        float e = 0.0f;
#pragma unroll
        for (int jj = 0; jj < 4; ++jj) {
            int zo = zg * 4 + jj;            // 0..15
            int zc = bz - 7 + zo;            // support really [bz-5, bz+7]
            float wt = 0.0f;
#pragma unroll
            for (int pz = 0; pz < 4; ++pz) {
                int d = zo - 6 - pz;         // zc - (bz+pz-1), bz cancels
                unsigned ud = (unsigned)(d + RADC);
                if (ud <= 2 * RADC) wt += wz[pz] * K.k[d < 0 ? -d : d];
            }
            if (wt != 0.0f)
                e += wt * field2[((zc + NGRID) & 127) * NG2 + xybase];
        }
        e *= wxy;
#pragma unroll
        for (int m = 32; m >= 1; m >>= 1) e += __shfl_xor(e, m, 64);
        if (lane == 0) out[i] = e;
    }
}

// ---------------------------------------------------------------------------
// Legacy 4-dispatch path (verified @117 µs) kept as runtime fallback in case
// cooperative launch is rejected (e.g., grid > co-resident capacity).
// ---------------------------------------------------------------------------
__global__ void scatter_wave(const int* __restrict__ z, const float* __restrict__ pos,
                             const float* __restrict__ emb,
                             const float* __restrict__ W0, const float* __restrict__ b0,
                             const float* __restrict__ W1, const float* __restrict__ b1,
                             float* __restrict__ field, int N) {
    int wave = threadIdx.x >> 6, lane = threadIdx.x & 63;
    int i = blockIdx.x * 4 + wave;
    if (i >= N) return;
    int sub = lane & 31;
    int zi = z[i];
    float x = emb[zi * CH + sub];

    float acc = b0[sub];
#pragma unroll
    for (int k = 0; k < CH; ++k)
        acc = fmaf(__shfl(x, k, 32), W0[sub * CH + k], acc);
    float h1 = silu(acc);

    acc = b1[sub];
#pragma unroll
    for (int k = 0; k < CH; ++k)
        acc = fmaf(__shfl(h1, k, 32), W1[sub * CH + k], acc);
    float s = silu(acc);
#pragma unroll
    for (int m = 16; m >= 1; m >>= 1) s += __shfl_xor(s, m, 32);

    float w; int addr;
    lane_tap(pos, i, lane, w, addr);
    atomicAdd(&field[addr], w * s);
}

#define LYT 32
#define LROWS (LYT + 2 * HALO)

__global__ void __launch_bounds__(256)
conv_xy(const float* __restrict__ fin, float* __restrict__ fout, Ktaps K) {
    __shared__ float sm[LROWS][NGRID];
    int zpl = blockIdx.x >> 2;
    int y0  = (blockIdx.x & 3) * LYT;
    int tid = threadIdx.x;
    const float* plane = fin + zpl * NG2;

    for (int idx = tid; idx < LROWS * NGRID; idx += 256) {
        int row = idx >> 7, x = idx & 127;
        int gy = (y0 + row - HALO) & (NGRID - 1);
        sm[row][x] = plane[gy * NGRID + x];
    }
    __syncthreads();

    int wave = tid >> 6, lane = tid & 63;
    for (int row = wave; row < LROWS; row += 4) {
        int t0 = lane, t1 = lane + 64;
        float a0 = K.k[0] * sm[row][t0];
        float a1 = K.k[0] * sm[row][t1];
#pragma unroll
        for (int r = 1; r <= RADC; ++r) {
            a0 += K.k[r] * (sm[row][(t0 + r) & 127] + sm[row][(t0 - r + 128) & 127]);
            a1 += K.k[r] * (sm[row][(t1 + r) & 127] + sm[row][(t1 - r + 128) & 127]);
        }
        sm[row][t0] = a0;
        sm[row][t1] = a1;
    }
    __syncthreads();

    int xl = tid & 127, yh = tid >> 7;
    float* oplane = fout + zpl * NG2;
    for (int j = yh; j < LYT; j += 2) {
        float acc = K.k[0] * sm[HALO + j][xl];
#pragma unroll
        for (int r = 1; r <= RADC; ++r)
            acc += K.k[r] * (sm[HALO + j + r][xl] + sm[HALO + j - r][xl]);
        oplane[(y0 + j) * NGRID + xl] = acc;
    }
}

__global__ void gather_z(const float* __restrict__ pos,
                         const float* __restrict__ field2,
                         float* __restrict__ out, Ktaps K, int N) {
    int wave = threadIdx.x >> 6, lane = threadIdx.x & 63;
    int i = blockIdx.x * 4 + wave;
    if (i >= N) return;
    int px = lane & 3, py = (lane >> 2) & 3, zg = lane >> 4;

    float pwx = fmodf(pos[i * 3 + 0], L_BOX);
    float pwy = fmodf(pos[i * 3 + 1], L_BOX);
    float pwz = fmodf(pos[i * 3 + 2], L_BOX);
    int bx = (int)floorf(pwx / H);
    int by = (int)floorf(pwy / H);
    int bz = (int)floorf(pwz / H);
    int cx = bx + px - 1, cy = by + py - 1;
    float dx = (pwx - (float)cx * H) / H;
    float dy = (pwy - (float)cy * H) / H;
    float wxy = expf(-0.5f * dx * dx) * expf(-0.5f * dy * dy);
    int ix = (cx + NGRID) & 127, iy = (cy + NGRID) & 127;

    float wz[4];
#pragma unroll
    for (int pz = 0; pz < 4; ++pz) {
        int cz = bz + pz - 1;
        float dz = (pwz - (float)cz * H) / H;
        wz[pz] = expf(-0.5f * dz * dz);
    }

    int xybase = iy * NGRID + ix;
    float e = 0.0f;
#pragma unroll
    for (int jj = 0; jj < 4; ++jj) {
        int zo = zg * 4 + jj;
        int zc = bz - 7 + zo;
        float wt = 0.0f;
#pragma unroll
        for (int pz = 0; pz < 4; ++pz) {
            int d = zo - 6 - pz;
            unsigned ud = (unsigned)(d + RADC);
            if (ud <= 2 * RADC) wt += wz[pz] * K.k[d < 0 ? -d : d];
        }
        if (wt != 0.0f)
            e += wt * field2[((zc + NGRID) & 127) * NG2 + xybase];
    }
    e *= wxy;
#pragma unroll
    for (int m = 32; m >= 1; m >>= 1) e += __shfl_xor(e, m, 64);
    if (lane == 0) out[i] = e;
}

extern "C" void kernel_launch(void* const* d_in, const int* in_sizes, int n_in,
                              void* d_out, int out_size, void* d_ws, size_t ws_size,
                              hipStream_t stream) {
    const int*   z   = (const int*)d_in[0];
    const float* pos = (const float*)d_in[1];
    // d_in[2] = batch: all zeros with NBATCH=1 -> no effect on flat index.
    const float* emb = (const float*)d_in[3];
    const float* W0  = (const float*)d_in[4];
    const float* b0  = (const float*)d_in[5];
    const float* W1  = (const float*)d_in[6];
    const float* b1  = (const float*)d_in[7];
    int N = in_sizes[0];

    float* field1 = (float*)d_ws;         // scatter target, 8 MB
    float* field2 = field1 + NG3;         // xy-conv output, 8 MB
    float* outp   = (float*)d_out;

    // Host-side exact periodic taps: inverse DFT of exp(-0.5*(2*pi*j'/NG)^2).
    Ktaps K;
    for (int r = 0; r <= RADC; ++r) {
        double acc = 0.0;
        for (int j = 0; j < NGRID; ++j) {
            int jj = (j < NGRID / 2) ? j : j - NGRID;
            double arg = (2.0 * M_PI * jj) / NGRID;   // sigma = h cancels
            acc += exp(-0.5 * arg * arg) * cos((2.0 * M_PI) * ((double)(j * r) / NGRID));
        }
        K.k[r] = (float)(acc / NGRID);
    }

    // Grid size: co-resident capacity (cooperative requirement), capped at
    // NTASK so the conv phase is 1 task/block. 256 CUs on MI355X.
    static int nb = 0;
    if (nb == 0) {
        int b = 0;
        if (hipOccupancyMaxActiveBlocksPerMultiprocessor(&b, fused, 256, 0) != hipSuccess || b < 1)
            b = 2;                        // 2 blocks/CU is safely resident (12 KB LDS, low VGPR)
        long cap = (long)b * 256;
        nb = (int)(cap < NTASK ? cap : NTASK);
    }

    void* args[12];
    args[0] = (void*)&z;  args[1] = (void*)&pos; args[2] = (void*)&emb;
    args[3] = (void*)&W0; args[4] = (void*)&b0;  args[5] = (void*)&W1;
    args[6] = (void*)&b1; args[7] = (void*)&field1; args[8] = (void*)&field2;
    args[9] = (void*)&outp; args[10] = (void*)&K; args[11] = (void*)&N;

    hipError_t e = hipLaunchCooperativeKernel((const void*)fused, dim3(nb), dim3(256),
                                              args, 0, stream);
    if (e != hipSuccess) {
        // Fallback: verified legacy 4-dispatch pipeline.
        hipMemsetAsync(field1, 0, NG3 * sizeof(float), stream);
        scatter_wave<<<(N + 3) / 4, 256, 0, stream>>>(z, pos, emb, W0, b0, W1, b1, field1, N);
        conv_xy<<<NGRID * 4, 256, 0, stream>>>(field1, field2, K);
        gather_z<<<(N + 3) / 4, 256, 0, stream>>>(pos, field2, outp, K, N);
    }
}

// Round 2
// 172.709 us; speedup vs baseline: 1.4258x; 1.4258x over previous
//
#include <hip/hip_runtime.h>
#include <math.h>

#define NGRID 128
#define CH 32
#define RADC 4            // taps kept: K[5..8]/K[0] < 4e-6 — below fp32 noise vs 3e-2 threshold

constexpr float L_BOX = 10.0f;
constexpr float H = L_BOX / NGRID;   // 0.078125 — exact in fp32

struct Ktaps { float k[RADC + 1]; };

__device__ __forceinline__ float silu(float v) {
    return v / (1.0f + expf(-v));
}

// ---------------------------------------------------------------------------
// Math: energy_i = sum_j s_j * Fx(i,j) * Fy(i,j) * Fz(i,j)
//   s_j   = sum_c MLP(emb[z_j])_c            (channel sum commutes with blur)
//   Faxis = sum_{p,q in 0..3} wi_p wj_q K[|db + p - q|],  db = (bi-bj) mod 128
// Support: |db| <= 7 per axis (K truncated at RADC=4, validated on grid path).
// This is EXACTLY the scatter->spectral-blur->gather chain with summation
// reordered per pair; same taps, same K, same truncation.
// ---------------------------------------------------------------------------

// Kernel A: one wave per particle. MLP via shuffles (verified body), then
// emit a 64 B record: {wx[4], wy[4], wz[4], s, cell_pack, 0, 0} + cp[] array.
__global__ void __launch_bounds__(256)
prep(const int* __restrict__ z, const float* __restrict__ pos,
     const float* __restrict__ emb,
     const float* __restrict__ W0, const float* __restrict__ b0,
     const float* __restrict__ W1, const float* __restrict__ b1,
     float* __restrict__ rec, int* __restrict__ cp, int N) {
    int wave = threadIdx.x >> 6, lane = threadIdx.x & 63;
    int i = blockIdx.x * 4 + wave;
    if (i >= N) return;                  // no barriers below: early-out safe
    int sub = lane & 31;                 // channel (both half-waves identical)
    int zi = z[i];
    float x = emb[zi * CH + sub];

    float acc = b0[sub];
#pragma unroll
    for (int k = 0; k < CH; ++k)
        acc = fmaf(__shfl(x, k, 32), W0[sub * CH + k], acc);
    float h1 = silu(acc);

    acc = b1[sub];
#pragma unroll
    for (int k = 0; k < CH; ++k)
        acc = fmaf(__shfl(h1, k, 32), W1[sub * CH + k], acc);
    float s = silu(acc);
#pragma unroll
    for (int m = 16; m >= 1; m >>= 1) s += __shfl_xor(s, m, 32);

    float pwx = fmodf(pos[i * 3 + 0], L_BOX);
    float pwy = fmodf(pos[i * 3 + 1], L_BOX);
    float pwz = fmodf(pos[i * 3 + 2], L_BOX);
    int bx = (int)floorf(pwx / H);       // in [0,127]
    int by = (int)floorf(pwy / H);
    int bz = (int)floorf(pwz / H);
    int cpv = bx | (by << 8) | (bz << 16);

    // lanes 0..11: tap weight for (axis = lane>>2, p = lane&3)
    int axis = lane >> 2, p = lane & 3;
    float pwa = (axis == 0) ? pwx : ((axis == 1) ? pwy : pwz);   // no dyn-idx arrays
    int   ba  = (axis == 0) ? bx  : ((axis == 1) ? by  : bz);
    int c = ba + p - 1;
    float d = (pwa - (float)c * H) / H;
    float w = expf(-0.5f * d * d);

    float val = (lane < 12) ? w
              : (lane == 12) ? s
              : (lane == 13) ? __int_as_float(cpv) : 0.0f;
    if (lane < 16) rec[i * 16 + lane] = val;
    if (lane == 0) cp[i] = cpv;
}

// Per-axis factor: F = sum_r A_r * K[|db + r|], r = p-q in [-3,3]
// A_r = correlation of the two 4-tap weight vectors. Kl has zeros for idx>4.
__device__ __forceinline__ float axis_factor(float4 wi, float4 wj, int db,
                                             const float* __restrict__ Kl) {
    float A0 = wi.x * wj.w;                                       // r=-3
    float A1 = wi.x * wj.z + wi.y * wj.w;                         // r=-2
    float A2 = wi.x * wj.y + wi.y * wj.z + wi.z * wj.w;           // r=-1
    float A3 = wi.x * wj.x + wi.y * wj.y + wi.z * wj.z + wi.w * wj.w; // r=0
    float A4 = wi.y * wj.x + wi.z * wj.y + wi.w * wj.z;           // r=+1
    float A5 = wi.z * wj.x + wi.w * wj.y;                         // r=+2
    float A6 = wi.w * wj.x;                                       // r=+3
    float f;
    f  = A0 * Kl[abs(db - 3)];           // |db|<=7, r in [-3,3] -> idx <= 10 < 16
    f += A1 * Kl[abs(db - 2)];
    f += A2 * Kl[abs(db - 1)];
    f += A3 * Kl[abs(db)];
    f += A4 * Kl[abs(db + 1)];
    f += A5 * Kl[abs(db + 2)];
    f += A6 * Kl[abs(db + 3)];
    return f;
}

// Kernel B: one wave per particle i. Lanes scan all j (coalesced 4 B reads of
// packed cells); periodic 3-axis window test via ((d+7)&127)<=14 + v_max3;
// rare passing lanes (~16 per wave over the whole scan) compute the factor.
__global__ void __launch_bounds__(256)
pair_energy(const float* __restrict__ rec, const int* __restrict__ cp,
            float* __restrict__ out, Ktaps K, int N) {
    __shared__ float Kl[16];
    int tid = threadIdx.x;
    if (tid < 16) Kl[tid] = (tid <= RADC) ? K.k[tid] : 0.0f;
    __syncthreads();                     // all waves reach this (no early-out)

    int wave = tid >> 6, lane = tid & 63;
    int i = blockIdx.x * 4 + wave;
    bool valid = i < N;
    int ii = valid ? i : 0;

    const float4* rec4 = (const float4*)rec;
    float4 a0 = rec4[ii * 4 + 0];        // wx_i
    float4 a1 = rec4[ii * 4 + 1];        // wy_i
    float4 a2 = rec4[ii * 4 + 2];        // wz_i
    int cpi = cp[ii];
    int bxi = cpi & 127, byi = (cpi >> 8) & 127, bzi = (cpi >> 16) & 127;

    float e = 0.0f;
#pragma unroll 4
    for (int j = lane; j < N; j += 64) {
        int cpj = cp[j];
        int dx = ((bxi - (cpj & 127)) + 7) & 127;          // db+7 mod 128
        int dy = ((byi - ((cpj >> 8) & 127)) + 7) & 127;
        int dz = ((bzi - ((cpj >> 16) & 127)) + 7) & 127;
        int m = max(dx, max(dy, dz));                      // v_max3_u32
        if (m <= 14) {                                     // all |db| <= 7
            float4 b0 = rec4[j * 4 + 0];
            float4 b1 = rec4[j * 4 + 1];
            float4 b2 = rec4[j * 4 + 2];
            float4 b3 = rec4[j * 4 + 3];                   // .x = s_j
            float fx = axis_factor(a0, b0, dx - 7, Kl);
            float fy = axis_factor(a1, b1, dy - 7, Kl);
            float fz = axis_factor(a2, b2, dz - 7, Kl);
            e += b3.x * fx * fy * fz;
        }
    }
#pragma unroll
    for (int m2 = 32; m2 >= 1; m2 >>= 1) e += __shfl_xor(e, m2, 64);
    if (valid && lane == 0) out[i] = e;
}

extern "C" void kernel_launch(void* const* d_in, const int* in_sizes, int n_in,
                              void* d_out, int out_size, void* d_ws, size_t ws_size,
                              hipStream_t stream) {
    const int*   z   = (const int*)d_in[0];
    const float* pos = (const float*)d_in[1];
    // d_in[2] = batch: all zeros with NBATCH=1 -> no effect.
    const float* emb = (const float*)d_in[3];
    const float* W0  = (const float*)d_in[4];
    const float* b0  = (const float*)d_in[5];
    const float* W1  = (const float*)d_in[6];
    const float* b1  = (const float*)d_in[7];
    int N = in_sizes[0];

    float* rec = (float*)d_ws;               // N * 16 floats (640 KB @ N=10000)
    int*   cp  = (int*)(rec + (size_t)N * 16);   // N ints

    // Host-side exact periodic taps: inverse DFT of exp(-0.5*(2*pi*j'/NG)^2).
    Ktaps K;
    for (int r = 0; r <= RADC; ++r) {
        double acc = 0.0;
        for (int j = 0; j < NGRID; ++j) {
            int jj = (j < NGRID / 2) ? j : j - NGRID;
            double arg = (2.0 * M_PI * jj) / NGRID;   // sigma = h cancels
            acc += exp(-0.5 * arg * arg) * cos((2.0 * M_PI) * ((double)(j * r) / NGRID));
        }
        K.k[r] = (float)(acc / NGRID);
    }

    int nb = (N + 3) / 4;
    prep<<<nb, 256, 0, stream>>>(z, pos, emb, W0, b0, W1, b1, rec, cp, N);
    pair_energy<<<nb, 256, 0, stream>>>(rec, cp, (float*)d_out, K, N);
}

// Round 3
// 117.761 us; speedup vs baseline: 2.0911x; 1.4666x over previous
//
#include <hip/hip_runtime.h>
#include <math.h>

#define NGRID 128
#define CH 32
#define RADC 4            // taps kept: K[5..8]/K[0] < 4e-6 — below fp32 noise vs 3e-2 threshold

constexpr float L_BOX = 10.0f;
constexpr float H = L_BOX / NGRID;   // 0.078125 — exact in fp32

struct Ktaps { float k[RADC + 1]; };

__device__ __forceinline__ float silu(float v) {
    return v / (1.0f + expf(-v));
}

// ---------------------------------------------------------------------------
// Math (verified in round 2, absmax 0.0039 vs 3e-2 threshold):
//   energy_i = sum_j s_j * Fx(i,j) * Fy(i,j) * Fz(i,j)
//   s_j   = sum_c MLP(emb[z_j])_c
//   Faxis = sum_{p,q in 0..3} wi_p wj_q K[|db + p - q|],  db = nearest-image (bi-bj)
// Support: |db| <= 7 per axis. This round adds (a) counting sort by bz so each
// wave scans only the 15-slab window (~1170 of 10000 j's, 1-2 contiguous
// ranges), and (b) ballot-compaction of hits so the ~100-op factor body runs
// lane-parallel instead of at ~2% lane utilization.
// ---------------------------------------------------------------------------

// Kernel A: one wave per particle. MLP via shuffles (verified body), then
// emit a 64 B record {wx[4], wy[4], wz[4], s, cpv, 0, 0} + packed cell cp[i].
__global__ void __launch_bounds__(256)
prep(const int* __restrict__ z, const float* __restrict__ pos,
     const float* __restrict__ emb,
     const float* __restrict__ W0, const float* __restrict__ b0,
     const float* __restrict__ W1, const float* __restrict__ b1,
     float* __restrict__ rec, int* __restrict__ cp, int N) {
    int wave = threadIdx.x >> 6, lane = threadIdx.x & 63;
    int i = blockIdx.x * 4 + wave;
    if (i >= N) return;                  // no barriers below: early-out safe
    int sub = lane & 31;                 // channel (both half-waves identical)
    int zi = z[i];
    float x = emb[zi * CH + sub];

    float acc = b0[sub];
#pragma unroll
    for (int k = 0; k < CH; ++k)
        acc = fmaf(__shfl(x, k, 32), W0[sub * CH + k], acc);
    float h1 = silu(acc);

    acc = b1[sub];
#pragma unroll
    for (int k = 0; k < CH; ++k)
        acc = fmaf(__shfl(h1, k, 32), W1[sub * CH + k], acc);
    float s = silu(acc);
#pragma unroll
    for (int m = 16; m >= 1; m >>= 1) s += __shfl_xor(s, m, 32);

    float pwx = fmodf(pos[i * 3 + 0], L_BOX);
    float pwy = fmodf(pos[i * 3 + 1], L_BOX);
    float pwz = fmodf(pos[i * 3 + 2], L_BOX);
    int bx = (int)floorf(pwx / H);       // in [0,127]
    int by = (int)floorf(pwy / H);
    int bz = (int)floorf(pwz / H);
    int cpv = bx | (by << 8) | (bz << 16);

    // lanes 0..11: tap weight for (axis = lane>>2, p = lane&3)
    int axis = lane >> 2, p = lane & 3;
    float pwa = (axis == 0) ? pwx : ((axis == 1) ? pwy : pwz);
    int   ba  = (axis == 0) ? bx  : ((axis == 1) ? by  : bz);
    int c = ba + p - 1;
    float d = (pwa - (float)c * H) / H;
    float w = expf(-0.5f * d * d);

    float val = (lane < 12) ? w
              : (lane == 12) ? s
              : (lane == 13) ? __int_as_float(cpv) : 0.0f;
    if (lane < 16) rec[i * 16 + lane] = val;
    if (lane == 0) cp[i] = cpv;
}

// Kernel B: single-block counting sort by bz (128 bins). Emits sorted packed
// cells cpS[], permutation perm[] (sorted slot -> original index), and
// binStart[129] prefix offsets. ~120 KB of traffic: a few microseconds.
__global__ void __launch_bounds__(1024)
binsort(const int* __restrict__ cp, int* __restrict__ cpS, int* __restrict__ perm,
        int* __restrict__ binStart, int N) {
    __shared__ int hist[129];
    __shared__ int cursor[128];
    int tid = threadIdx.x;
    if (tid < 129) hist[tid] = 0;
    __syncthreads();
    for (int i = tid; i < N; i += 1024)
        atomicAdd(&hist[(cp[i] >> 16) & 127], 1);
    __syncthreads();
    if (tid == 0) {                      // 128-step serial exclusive scan: ~0.5 us
        int acc = 0;
        for (int b = 0; b < 128; ++b) { int c = hist[b]; hist[b] = acc; acc += c; }
        hist[128] = acc;
    }
    __syncthreads();
    if (tid < 128) cursor[tid] = hist[tid];
    if (tid < 129) binStart[tid] = hist[tid];
    __syncthreads();
    for (int i = tid; i < N; i += 1024) {
        int c = cp[i];
        int dst = atomicAdd(&cursor[(c >> 16) & 127], 1);
        cpS[dst] = c;
        perm[dst] = i;
    }
}

// Per-axis factor: F = sum_r A_r * K[|db + r|], r = p-q in [-3,3], db in [-7,7].
// Kl has zeros for idx>4 so indices up to 10 are safe.
__device__ __forceinline__ float axis_factor(float4 wi, float4 wj, int db,
                                             const float* __restrict__ Kl) {
    float A0 = wi.x * wj.w;
    float A1 = wi.x * wj.z + wi.y * wj.w;
    float A2 = wi.x * wj.y + wi.y * wj.z + wi.z * wj.w;
    float A3 = wi.x * wj.x + wi.y * wj.y + wi.z * wj.z + wi.w * wj.w;
    float A4 = wi.y * wj.x + wi.z * wj.y + wi.w * wj.z;
    float A5 = wi.z * wj.x + wi.w * wj.y;
    float A6 = wi.w * wj.x;
    float f;
    f  = A0 * Kl[abs(db - 3)];
    f += A1 * Kl[abs(db - 2)];
    f += A2 * Kl[abs(db - 1)];
    f += A3 * Kl[abs(db)];
    f += A4 * Kl[abs(db + 1)];
    f += A5 * Kl[abs(db + 2)];
    f += A6 * Kl[abs(db + 3)];
    return f;
}

// Full pair term for sorted slot j (lane-parallel in the compacted pass).
__device__ __forceinline__ float hit_term(int j, const float4* __restrict__ rec4,
                                          const int* __restrict__ cpS,
                                          const int* __restrict__ perm,
                                          int bxi, int byi, int bzi,
                                          float4 a0, float4 a1, float4 a2,
                                          const float* __restrict__ Kl) {
    int cpj = cpS[j];
    int p = perm[j];
    int dx = (((bxi - (cpj & 127)) + 7) & 127) - 7;          // nearest-image db
    int dy = (((byi - ((cpj >> 8) & 127)) + 7) & 127) - 7;
    int dz = (((bzi - ((cpj >> 16) & 127)) + 7) & 127) - 7;
    float4 b0 = rec4[p * 4 + 0];
    float4 b1 = rec4[p * 4 + 1];
    float4 b2 = rec4[p * 4 + 2];
    float4 b3 = rec4[p * 4 + 3];                             // .x = s_j
    float fx = axis_factor(a0, b0, dx, Kl);
    float fy = axis_factor(a1, b1, dy, Kl);
    float fz = axis_factor(a2, b2, dz, Kl);
    return b3.x * fx * fy * fz;
}

// Kernel C: one wave per particle i. Scans the 15-z-slab window as 1-2
// contiguous sorted ranges; ballot-compacts passing j's into a per-wave LDS
// buffer; processes 64 hits lane-parallel per flush.
__global__ void __launch_bounds__(256)
pair_energy(const float* __restrict__ rec, const int* __restrict__ cp,
            const int* __restrict__ cpS, const int* __restrict__ perm,
            const int* __restrict__ binStart,
            float* __restrict__ out, Ktaps K, int N) {
    __shared__ float Kl[16];
    __shared__ int hitbuf[4][128];
    int tid = threadIdx.x;
    if (tid < 16) Kl[tid] = (tid <= RADC) ? K.k[tid] : 0.0f;
    __syncthreads();                     // all waves reach this (no early-out)

    int wave = tid >> 6, lane = tid & 63;
    int i = blockIdx.x * 4 + wave;
    bool valid = i < N;
    int ii = valid ? i : 0;

    const float4* rec4 = (const float4*)rec;
    float4 a0 = rec4[ii * 4 + 0];        // wx_i
    float4 a1 = rec4[ii * 4 + 1];        // wy_i
    float4 a2 = rec4[ii * 4 + 2];        // wz_i
    int cpi = cp[ii];
    int bxi = cpi & 127, byi = (cpi >> 8) & 127, bzi = (cpi >> 16) & 127;

    // z-window bins [bzi-7, bzi+7] mod 128 -> 1 or 2 contiguous sorted ranges
    int lo = bzi - 7, hi = bzi + 7;
    int r0lo, r0hi, r1lo, r1hi;
    if (lo >= 0 && hi <= 127) { r0lo = binStart[lo]; r0hi = binStart[hi + 1]; r1lo = 0; r1hi = 0; }
    else if (lo < 0)          { r0lo = 0;            r0hi = binStart[hi + 1]; r1lo = binStart[lo + 128]; r1hi = N; }
    else                      { r0lo = binStart[lo]; r0hi = N;                r1lo = 0; r1hi = binStart[hi - 127]; }

    int* hb = hitbuf[wave];              // wave-private: no __syncthreads needed
    int cnt = 0;
    float e = 0.0f;

#pragma unroll
    for (int rr = 0; rr < 2; ++rr) {
        int jlo = rr ? r1lo : r0lo;
        int jhi = rr ? r1hi : r0hi;
        for (int jb = jlo; jb < jhi; jb += 64) {
            int j = jb + lane;
            int jc = min(j, N - 1);
            int cpj = cpS[jc];
            int dx = ((bxi - (cpj & 127)) + 7) & 127;
            int dy = ((byi - ((cpj >> 8) & 127)) + 7) & 127;
            int dz = ((bzi - ((cpj >> 16) & 127)) + 7) & 127;
            int m = max(dx, max(dy, dz));          // v_max3
            bool pass = (j < jhi) && (m <= 14);
            unsigned long long mask = __ballot(pass);
            int myoff = __popcll(mask & ((1ull << lane) - 1ull));
            if (pass) hb[cnt + myoff] = j;         // cnt<64, append<=64 -> <=127
            __builtin_amdgcn_wave_barrier();       // keep LDS RAW ordered in-wave
            cnt += (int)__popcll(mask);
            if (cnt >= 64) {
                e += hit_term(hb[lane], rec4, cpS, perm, bxi, byi, bzi, a0, a1, a2, Kl);
                cnt -= 64;
                __builtin_amdgcn_wave_barrier();
                int mv = (lane < cnt) ? hb[64 + lane] : 0;   // shift leftovers down
                __builtin_amdgcn_wave_barrier();
                if (lane < cnt) hb[lane] = mv;
                __builtin_amdgcn_wave_barrier();
            }
        }
    }
    if (lane < cnt)
        e += hit_term(hb[lane], rec4, cpS, perm, bxi, byi, bzi, a0, a1, a2, Kl);

#pragma unroll
    for (int m2 = 32; m2 >= 1; m2 >>= 1) e += __shfl_xor(e, m2, 64);
    if (valid && lane == 0) out[i] = e;
}

extern "C" void kernel_launch(void* const* d_in, const int* in_sizes, int n_in,
                              void* d_out, int out_size, void* d_ws, size_t ws_size,
                              hipStream_t stream) {
    const int*   z   = (const int*)d_in[0];
    const float* pos = (const float*)d_in[1];
    // d_in[2] = batch: all zeros with NBATCH=1 -> no effect.
    const float* emb = (const float*)d_in[3];
    const float* W0  = (const float*)d_in[4];
    const float* b0  = (const float*)d_in[5];
    const float* W1  = (const float*)d_in[6];
    const float* b1  = (const float*)d_in[7];
    int N = in_sizes[0];

    float* rec      = (float*)d_ws;                    // N*16 floats
    int*   cp       = (int*)(rec + (size_t)N * 16);    // N
    int*   cpS      = cp + N;                          // N
    int*   perm     = cpS + N;                         // N
    int*   binStart = perm + N;                        // 129

    // Host-side exact periodic taps: inverse DFT of exp(-0.5*(2*pi*j'/NG)^2).
    Ktaps K;
    for (int r = 0; r <= RADC; ++r) {
        double acc = 0.0;
        for (int j = 0; j < NGRID; ++j) {
            int jj = (j < NGRID / 2) ? j : j - NGRID;
            double arg = (2.0 * M_PI * jj) / NGRID;   // sigma = h cancels
            acc += exp(-0.5 * arg * arg) * cos((2.0 * M_PI) * ((double)(j * r) / NGRID));
        }
        K.k[r] = (float)(acc / NGRID);
    }

    int nb = (N + 3) / 4;
    prep<<<nb, 256, 0, stream>>>(z, pos, emb, W0, b0, W1, b1, rec, cp, N);
    binsort<<<1, 1024, 0, stream>>>(cp, cpS, perm, binStart, N);
    pair_energy<<<nb, 256, 0, stream>>>(rec, cp, cpS, perm, binStart,
                                        (float*)d_out, K, N);
}